// Round 3
// baseline (589.788 us; speedup 1.0000x reference)
//
#include <hip/hip_runtime.h>
#include <math.h>

#define BB 32
#define TT 720
#define NNN 321
#define KK 25
#define PP 12
#define TCH 24   // T-chunk per thread in mavg; 720 = 30 * 24

constexpr int L0 = BB * TT * NNN;          // 7,395,840
constexpr int L1 = (L0 + 15) / 2;          // 3,697,927
constexpr int L2 = (L1 + 15) / 2;          // 1,848,971
constexpr int L3 = (L2 + 15) / 2;          // 924,493
constexpr unsigned KMED = (unsigned)((L1 - 1) / 2 + 1);
constexpr float AA = 0.85f;

// median pass-1 compaction geometry: 512 blocks, contiguous chunks
constexpr int NH1B = 512;                       // hist1 blocks per signal
constexpr int CH   = (L1 + NH1B - 1) / NH1B;    // 7223 elements/block
constexpr int CANDSZ = NH1B * CH;               // per-signal cand region

// fused-kernel tile params
#define NC3 1024                            // ca3 outputs per block in dwt123
constexpr int LEN2T = 2 * NC3 + 32;         // ca2 tile slots (raw T0 = 2*C0-14)
constexpr int LEN1T = 4 * NC3 + 80;         // ca1 tile slots (= len1 max)
#define NF0 4096                            // final outputs per block in idwt_fused (div by 8)
constexpr int N1T = NF0 / 2 + 8;            // 2056 rec1 tile
constexpr int N2T = N1T / 2 + 7;            // 1035 rec2 tile
constexpr int NQ3 = (N2T + 1) / 2;          // 518 rec2 pairs

// 16-tap analysis low-pass (from reference)
constexpr float DLO[16] = {
    -0.0033824159510061256f, -0.0005421323317911481f, 0.03169508781149298f,
    0.007607487324917605f,  -0.1432942383508097f,    -0.061273359067658524f,
    0.4813596512583722f,     0.7771857517005235f,     0.36444189483533895f,
    -0.05194583810770904f,  -0.027219029917056003f,   0.049137179673607506f,
    0.003808752013890615f,  -0.01495225833704823f,   -0.0003029205147213668f,
    0.0018899503327594609f };

// ---------------- inline radix-select (run by last block of producer) ----------
// Reads hist via atomicExch (device-scope, cross-XCD safe) which also re-zeroes
// the bins for the next pass. 256 threads required.
__device__ void select_body(unsigned* hist, unsigned* prefix, unsigned* kArr,
                            float* lamArr, int nbins, int shift) {
    int t = threadIdx.x;
    int chunk = nbins >> 8;                 // 16 or 1
    __shared__ unsigned wsum[4];
    for (int s = 0; s < 2; ++s) {
        unsigned loc[16];
        unsigned* hs = hist + s * 4096 + t * chunk;
        unsigned csum = 0;
        for (int j = 0; j < chunk; ++j) { loc[j] = atomicExch(&hs[j], 0u); csum += loc[j]; }
        unsigned v = csum;
        int lane = t & 63, wv = t >> 6;
#pragma unroll
        for (int off = 1; off < 64; off <<= 1) {
            unsigned u = (unsigned)__shfl_up((int)v, off, 64);
            if (lane >= off) v += u;
        }
        if (lane == 63) wsum[wv] = v;
        __syncthreads();
        unsigned base = 0;
        for (int w2 = 0; w2 < wv; ++w2) base += wsum[w2];
        unsigned incl = base + v, excl = incl - csum;
        unsigned k = kArr[s];
        if (excl < k && incl >= k) {
            unsigned run = excl;
            for (int j = 0; j < chunk; ++j) {
                if (run < k && run + loc[j] >= k) {
                    unsigned digit = (unsigned)(t * chunk + j);
                    unsigned npref = prefix[s] | (digit << shift);
                    prefix[s] = npref;
                    kArr[s] = k - run;
                    if (shift == 0) {
                        float med = __uint_as_float(npref);
                        lamArr[s] = (med / 0.6745f) * sqrtf(2.0f * logf((float)L0));
                    }
                    break;
                }
                run += loc[j];
            }
        }
        __syncthreads();                    // wsum reuse for next s
    }
}

// last-block detection: fence, sync, one atomicAdd; returns true in last block
__device__ bool i_am_last(unsigned* done, unsigned nBlocks) {
    __shared__ int amLast;
    __threadfence();
    __syncthreads();
    if (threadIdx.x == 0) {
        unsigned prev = atomicAdd(done, 1u);
        amLast = (prev == nBlocks - 1) ? 1 : 0;
    }
    __syncthreads();
    return amLast != 0;
}

// ---------------- moving average + residual (+ median state init) ---------------
__global__ void mavg_kernel(const float* __restrict__ x,
                            float* __restrict__ trend,
                            float* __restrict__ res,
                            unsigned* __restrict__ hist,
                            unsigned* __restrict__ prefix,
                            unsigned* __restrict__ kArr,
                            unsigned* __restrict__ done) {
    constexpr int NCH = TT / TCH;                 // 30
    int gid = blockIdx.x * blockDim.x + threadIdx.x;
    // fold init_median here (consumed by later kernels; stream order guarantees)
    if (gid < 8192) hist[gid] = 0;
    if (gid < 2) { prefix[gid] = 0; kArr[gid] = KMED; }
    if (gid < 3) done[gid] = 0;
    if (gid >= BB * NCH * NNN) return;
    int n    = gid % NNN;
    int rest = gid / NNN;
    int ch   = rest % NCH;
    int b    = rest / NCH;
    int t0   = ch * TCH;
    const float* xb = x + (size_t)b * TT * NNN + n;
    float sum = 0.f;
#pragma unroll
    for (int dt = -PP; dt <= PP; ++dt) {
        int tt = t0 + dt;
        tt = tt < 0 ? 0 : (tt >= TT ? TT - 1 : tt);
        sum += xb[(size_t)tt * NNN];
    }
    size_t base = (size_t)b * TT * NNN + (size_t)t0 * NNN + n;
    for (int i = 0; i < TCH; ++i) {
        int t = t0 + i;
        float tr = sum * (1.0f / (float)KK);
        size_t idx = base + (size_t)i * NNN;
        trend[idx] = tr;
        res[idx] = xb[(size_t)t * NNN] - tr;
        int tp = t + 1 + PP; if (tp > TT - 1) tp = TT - 1;
        int tm = t - PP;     if (tm < 0)      tm = 0;
        sum += xb[(size_t)tp * NNN] - xb[(size_t)tm * NNN];
    }
}

// ---------------- fused DWT levels 1+2+3 (+ hist pass 0 + inline select0) -------
__global__ void dwt123_kernel(const float* __restrict__ trend,
                              const float* __restrict__ res,
                              float* __restrict__ cd1,
                              float* __restrict__ cd2,
                              float* __restrict__ ca3,
                              float* __restrict__ cd3,
                              unsigned* __restrict__ hist,
                              unsigned* __restrict__ prefix,
                              unsigned* __restrict__ kArr,
                              float* __restrict__ lamArr,
                              unsigned* __restrict__ done) {
    int s = blockIdx.y;
    int C0 = blockIdx.x * NC3;
    const float* a0 = s ? res : trend;           // level-1 input, length L0
    __shared__ float s1[LEN1T];                  // ca1 tile
    __shared__ float s2[LEN2T];                  // ca2 tile
    __shared__ unsigned sh[4096];                // pass-0 histogram
    for (int b = threadIdx.x; b < 4096; b += 256) sh[b] = 0;
    __syncthreads();

    int T0 = 2 * C0 - 14;
    int S1 = 4 * C0 - 42; if (S1 < 0) S1 = 0;
    int E1 = 2 * (T0 + LEN2T) + 2; if (E1 > L1) E1 = L1;
    int len1 = E1 - S1;                          // <= LEN1T
    float* pcd1 = cd1 + (size_t)s * L1;

    // ---- stage 1: level-1 DWT from global trend/res -> s1 (ca) + global cd1 core
    int npair = (len1 + 1) / 2;
    for (int ip = threadIdx.x; ip < npair; ip += 256) {
        int i = 2 * ip;
        int o = S1 + i;                          // ca1/cd1 output index (pair o, o+1)
        float slo0, shi0, slo1, shi1;
        if (2 * o - 14 >= 0 && 2 * o + 3 < L0) {
            const float* p = a0 + 2 * o - 14;
            float v[18];
#pragma unroll
            for (int j = 0; j < 18; ++j) v[j] = p[j];
            slo0 = shi0 = slo1 = shi1 = 0.f;
#pragma unroll
            for (int j = 0; j < 16; ++j) {
                float h = (j & 1) ? DLO[15 - j] : -DLO[15 - j];
                slo0 = fmaf(DLO[j], v[15 - j], slo0);
                shi0 = fmaf(h,      v[15 - j], shi0);
                slo1 = fmaf(DLO[j], v[17 - j], slo1);
                shi1 = fmaf(h,      v[17 - j], shi1);
            }
        } else {
            float acc[2][2];
#pragma unroll
            for (int q = 0; q < 2; ++q) {
                int oo = o + q;
                float slo = 0.f, shi = 0.f;
                int bidx = 2 * oo + 1;
#pragma unroll
                for (int j = 0; j < 16; ++j) {
                    int idx = bidx - j;
                    if (idx < 0) idx = -1 - idx;
                    if (idx >= L0) idx = 2 * L0 - 1 - idx;
                    float v = a0[idx];
                    slo = fmaf(DLO[j], v, slo);
                    float h = (j & 1) ? DLO[15 - j] : -DLO[15 - j];
                    shi = fmaf(h, v, shi);
                }
                acc[q][0] = slo; acc[q][1] = shi;
            }
            slo0 = acc[0][0]; shi0 = acc[0][1];
            slo1 = acc[1][0]; shi1 = acc[1][1];
        }
        s1[i] = slo0;
        if (o >= 4 * C0 && o < 4 * C0 + 4 * NC3) {
            pcd1[o] = shi0;
            atomicAdd(&sh[__float_as_uint(fabsf(shi0)) >> 20], 1u);
        }
        if (i + 1 < len1) {
            s1[i + 1] = slo1;
            int o1 = o + 1;
            if (o1 >= 4 * C0 && o1 < 4 * C0 + 4 * NC3) {
                pcd1[o1] = shi1;
                atomicAdd(&sh[__float_as_uint(fabsf(shi1)) >> 20], 1u);
            }
        }
    }
    __syncthreads();

    // flush pass-0 histogram (global-atomic latency overlaps stage 2)
    for (int b = threadIdx.x; b < 4096; b += 256) {
        unsigned c = sh[b];
        if (c) atomicAdd(&hist[s * 4096 + b], c);
    }

    // ---- stage 2: level-2 DWT from s1 -> s2 (ca2) + global cd2 core
    float* pcd2 = cd2 + (size_t)s * L2;
    for (int i = threadIdx.x; i < LEN2T; i += 256) {
        int e = T0 + i;
        if (e < 0 || e >= L2) continue;
        int base = 2 * e + 1;
        float slo = 0.f, shi = 0.f;
#pragma unroll
        for (int j = 0; j < 16; ++j) {
            int idx = base - j;
            if (idx < 0) idx = -1 - idx;
            if (idx >= L1) idx = 2 * L1 - 1 - idx;
            float v = s1[idx - S1];
            slo = fmaf(DLO[j], v, slo);
            float h = (j & 1) ? DLO[15 - j] : -DLO[15 - j];
            shi = fmaf(h, v, shi);
        }
        s2[i] = slo;
        if (e >= 2 * C0 && e < 2 * C0 + 2 * NC3) pcd2[e] = shi;
    }
    __syncthreads();
    // reflection fill for out-of-range ca2 tile slots (edges only)
    for (int i = threadIdx.x; i < LEN2T; i += 256) {
        int e = T0 + i;
        if (e < 0)        s2[i] = s2[(-1 - e) - T0];
        else if (e >= L2) s2[i] = s2[(2 * L2 - 1 - e) - T0];
    }
    __syncthreads();
    // ---- stage 3: level-3 DWT from s2
    float* pca3 = ca3 + (size_t)s * L3;
    float* pcd3 = cd3 + (size_t)s * L3;
    for (int i = threadIdx.x; i < NC3; i += 256) {
        int o = C0 + i;
        if (o >= L3) break;
        int b2 = 2 * o + 1 - T0;
        float slo = 0.f, shi = 0.f;
#pragma unroll
        for (int j = 0; j < 16; ++j) {
            float v = s2[b2 - j];
            slo = fmaf(DLO[j], v, slo);
            float h = (j & 1) ? DLO[15 - j] : -DLO[15 - j];
            shi = fmaf(h, v, shi);
        }
        pca3[o] = slo;
        pcd3[o] = shi;
    }

    // ---- last block runs select pass 0 (top 12 bits)
    if (i_am_last(done + 0, gridDim.x * gridDim.y))
        select_body(hist, prefix, kArr, lamArr, 4096, 20);
}

// ---------------- soft threshold ----------------
__device__ __forceinline__ float sthr(float d, float lam, float alam) {
    float ad = fabsf(d);
    return (ad >= lam) ? copysignf(ad - alam, d) : 0.f;
}

// ---------------- fused 3-level IDWT + final outputs ----------------
__global__ void idwt_fused(const float* __restrict__ ca3,
                           const float* __restrict__ cd3,
                           const float* __restrict__ cd2,
                           const float* __restrict__ cd1,
                           const float* __restrict__ trend,
                           const float* __restrict__ res,
                           float* __restrict__ out,
                           const float* __restrict__ lamArr) {
    int s = blockIdx.y;
    int F0 = blockIdx.x * NF0;
    float lam = lamArr[s], alam = AA * lam;
    const float* pa3 = ca3 + (size_t)s * L3;
    const float* pd3 = cd3 + (size_t)s * L3;
    const float* pd2 = cd2 + (size_t)s * L2;
    const float* pd1 = cd1 + (size_t)s * L1;
    __shared__ float r2[N2T + 1];
    __shared__ float r1[N1T];
    int A1 = F0 >> 1, A2 = F0 >> 2, Q3 = F0 >> 3;
    // stage rec2 tile from ca3/cd3 (level 3 -> 2)
    for (int i = threadIdx.x; i < NQ3; i += 256) {
        int q3 = Q3 + i;
        float a0 = 0.f, a1 = 0.f;
#pragma unroll
        for (int p = 0; p < 8; ++p) {
            int idx = q3 + p; if (idx > L3 - 1) idx = L3 - 1;
            float a = pa3[idx];
            float d = sthr(pd3[idx], lam, alam);
            a0 = fmaf(a, DLO[2 * p + 1], a0);
            a0 = fmaf(d, DLO[14 - 2 * p], a0);
            a1 = fmaf(a, DLO[2 * p], a1);
            a1 = fmaf(d, -DLO[15 - 2 * p], a1);
        }
        r2[2 * i] = a0; r2[2 * i + 1] = a1;
    }
    __syncthreads();
    // stage rec1 tile from rec2(LDS) + cd2(global) (level 2 -> 1)
    for (int i = threadIdx.x; i < N1T / 2; i += 256) {
        int q2 = A2 + i;
        float a0 = 0.f, a1 = 0.f;
#pragma unroll
        for (int p = 0; p < 8; ++p) {
            float a = r2[i + p];
            int idx = q2 + p; if (idx > L2 - 1) idx = L2 - 1;
            float d = sthr(pd2[idx], lam, alam);
            a0 = fmaf(a, DLO[2 * p + 1], a0);
            a0 = fmaf(d, DLO[14 - 2 * p], a0);
            a1 = fmaf(a, DLO[2 * p], a1);
            a1 = fmaf(d, -DLO[15 - 2 * p], a1);
        }
        r1[2 * i] = a0; r1[2 * i + 1] = a1;
    }
    __syncthreads();
    // final level from rec1(LDS) + cd1(global): 4 outputs/thread, float4 I/O
    const float* orig = s ? res : trend;
    float* o_diff = out + (size_t)(2 * s) * L0;
    float* o_nn   = out + (size_t)(2 * s + 1) * L0;
    for (int i = threadIdx.x; i < NF0 / 4; i += 256) {
        int ii = 2 * i;                      // r1-local index of first q1
        int q1 = A1 + ii;
        int r0 = 2 * q1;                     // multiple of 4; L0 % 4 == 0
        if (r0 >= L0) break;
        float d[9];
#pragma unroll
        for (int p = 0; p < 9; ++p) {
            int idx = q1 + p; if (idx > L1 - 1) idx = L1 - 1;
            d[p] = sthr(pd1[idx], lam, alam);
        }
        float a0 = 0.f, a1 = 0.f, b0 = 0.f, b1 = 0.f;
#pragma unroll
        for (int p = 0; p < 8; ++p) {
            float a  = r1[ii + p];
            float ab = r1[ii + 1 + p];
            a0 = fmaf(a,      DLO[2 * p + 1], a0);
            a0 = fmaf(d[p],   DLO[14 - 2 * p], a0);
            a1 = fmaf(a,      DLO[2 * p], a1);
            a1 = fmaf(d[p],  -DLO[15 - 2 * p], a1);
            b0 = fmaf(ab,     DLO[2 * p + 1], b0);
            b0 = fmaf(d[p+1], DLO[14 - 2 * p], b0);
            b1 = fmaf(ab,     DLO[2 * p], b1);
            b1 = fmaf(d[p+1],-DLO[15 - 2 * p], b1);
        }
        float4 o4 = *(const float4*)(orig + r0);
        float4 nn; nn.x = a0; nn.y = a1; nn.z = b0; nn.w = b1;
        float4 df; df.x = o4.x - a0; df.y = o4.y - a1; df.z = o4.z - b0; df.w = o4.w - b1;
        *(float4*)(o_nn + r0)   = nn;
        *(float4*)(o_diff + r0) = df;
    }
}

// pass 1: contiguous per-block chunks; filter on 12-bit prefix, histogram
// next 12 bits, compact survivors into the block's PRIVATE cand region.
// Last block runs select pass 1 inline.
__global__ void hist1_kernel(const float* __restrict__ d,
                             unsigned* __restrict__ hist,
                             unsigned* __restrict__ prefix,
                             unsigned* __restrict__ cand,
                             unsigned* __restrict__ bcnt,
                             unsigned* __restrict__ kArr,
                             float* __restrict__ lamArr,
                             unsigned* __restrict__ done) {
    int s = blockIdx.y;
    int blk = blockIdx.x;
    const float* ds = d + (size_t)s * L1;
    unsigned* cs = cand + (size_t)s * CANDSZ + (size_t)blk * CH;
    __shared__ unsigned sh[4096];
    __shared__ unsigned slocal;
    for (int b = threadIdx.x; b < 4096; b += 256) sh[b] = 0;
    if (threadIdx.x == 0) slocal = 0;
    __syncthreads();
    unsigned pref = prefix[s] >> 20;
    int i0 = blk * CH;
    int i1 = i0 + CH; if (i1 > L1) i1 = L1;
    for (int i = i0 + threadIdx.x; i < i1; i += 256) {
        unsigned u = __float_as_uint(fabsf(ds[i]));
        if ((u >> 20) == pref) {
            atomicAdd(&sh[(u >> 8) & 0xFFFu], 1u);
            unsigned pos = atomicAdd(&slocal, 1u);
            cs[pos] = u;
        }
    }
    __syncthreads();
    if (threadIdx.x == 0) bcnt[s * NH1B + blk] = slocal;
    for (int b = threadIdx.x; b < 4096; b += 256) {
        unsigned c = sh[b];
        if (c) atomicAdd(&hist[s * 4096 + b], c);
    }
    if (i_am_last(done + 1, gridDim.x * gridDim.y))
        select_body(hist, prefix, kArr, lamArr, 4096, 8);
}

// pass 2: last 8 bits over the compacted per-block candidate lists (tiny).
// Last block runs final select + lambda computation inline.
__global__ void hist2_kernel(const unsigned* __restrict__ cand,
                             unsigned* __restrict__ hist,
                             unsigned* __restrict__ prefix,
                             const unsigned* __restrict__ bcnt,
                             unsigned* __restrict__ kArr,
                             float* __restrict__ lamArr,
                             unsigned* __restrict__ done) {
    int s = blockIdx.y;
    int blk = blockIdx.x;
    const unsigned* cs = cand + (size_t)s * CANDSZ + (size_t)blk * CH;
    __shared__ unsigned sh[256];
    sh[threadIdx.x] = 0;
    __syncthreads();
    unsigned pref = prefix[s] >> 8;
    unsigned n = bcnt[s * NH1B + blk];
    for (unsigned i = threadIdx.x; i < n; i += 256) {
        unsigned u = cs[i];
        if ((u >> 8) == pref) atomicAdd(&sh[u & 0xFFu], 1u);
    }
    __syncthreads();
    unsigned c = sh[threadIdx.x];
    if (c) atomicAdd(&hist[s * 4096 + threadIdx.x], c);
    if (i_am_last(done + 2, gridDim.x * gridDim.y))
        select_body(hist, prefix, kArr, lamArr, 256, 0);
}

extern "C" void kernel_launch(void* const* d_in, const int* in_sizes, int n_in,
                              void* d_out, int out_size, void* d_ws, size_t ws_size,
                              hipStream_t stream) {
    const float* x = (const float*)d_in[0];
    float* out = (float*)d_out;
    float* w = (float*)d_ws;

    float* trend = w;
    float* res   = w + (size_t)L0;
    float* cd1   = w + 2 * (size_t)L0;
    float* cd2   = cd1 + 2 * (size_t)L1;
    float* ca3   = cd2 + 2 * (size_t)L2;
    float* cd3   = ca3 + 2 * (size_t)L3;
    unsigned* cand   = (unsigned*)(cd3 + 2 * (size_t)L3);
    unsigned* hist   = cand + 2 * (size_t)CANDSZ;
    unsigned* prefix = hist + 8192;
    unsigned* kArr   = prefix + 2;
    float*    lamArr = (float*)(kArr + 2);
    unsigned* bcnt   = (unsigned*)(lamArr + 2);   // 2 * NH1B entries
    unsigned* done   = bcnt + 2 * NH1B;           // 3 done-counters

    dim3 b256(256);

    {
        int nthreads = BB * (TT / TCH) * NNN;
        mavg_kernel<<<(nthreads + 255) / 256, b256, 0, stream>>>(
            x, trend, res, hist, prefix, kArr, done);
    }
    // fused 3-level decomposition + pass-0 histogram + inline select0
    dwt123_kernel<<<dim3((L3 + NC3 - 1) / NC3, 2), b256, 0, stream>>>(
        trend, res, cd1, cd2, ca3, cd3, hist, prefix, kArr, lamArr, done);
    // pass-1 histogram + compaction + inline select1
    hist1_kernel<<<dim3(NH1B, 2), b256, 0, stream>>>(
        cd1, hist, prefix, cand, bcnt, kArr, lamArr, done);
    // pass-2 histogram over candidates + inline select2 (computes lambda)
    hist2_kernel<<<dim3(NH1B, 2), b256, 0, stream>>>(
        cand, hist, prefix, bcnt, kArr, lamArr, done);
    // fused 3-level reconstruction + output
    idwt_fused<<<dim3((L0 + NF0 - 1) / NF0, 2), b256, 0, stream>>>(
        ca3, cd3, cd2, cd1, trend, res, out, lamArr);
}

// Round 4
// 329.132 us; speedup vs baseline: 1.7920x; 1.7920x over previous
//
#include <hip/hip_runtime.h>
#include <math.h>

#define BB 32
#define TT 720
#define NNN 321
#define KK 25
#define PP 12
#define TCH 24   // T-chunk per thread in mavg; 720 = 30 * 24

constexpr int L0 = BB * TT * NNN;          // 7,395,840
constexpr int L1 = (L0 + 15) / 2;          // 3,697,927
constexpr int L2 = (L1 + 15) / 2;          // 1,848,971
constexpr int L3 = (L2 + 15) / 2;          // 924,493
constexpr unsigned KMED = (unsigned)((L1 - 1) / 2 + 1);
constexpr float AA = 0.85f;

// median pass-1 compaction geometry: 512 blocks, contiguous chunks
constexpr int NH1B = 512;                       // hist1 blocks per signal
constexpr int CH   = (L1 + NH1B - 1) / NH1B;    // 7223 elements/block
constexpr int CANDSZ = NH1B * CH;               // per-signal cand region

// fused-kernel tile params
#define NC3 1024                            // ca3 outputs per block in dwt123
constexpr int LEN2T = 2 * NC3 + 32;         // ca2 tile slots (raw T0 = 2*C0-14)
constexpr int LEN1T = 4 * NC3 + 80;         // ca1 tile slots (= len1 max)
#define NF0 4096                            // final outputs per block in idwt_fused (div by 8)
constexpr int N1T = NF0 / 2 + 8;            // 2056 rec1 tile
constexpr int N2T = N1T / 2 + 7;            // 1035 rec2 tile
constexpr int NQ3 = (N2T + 1) / 2;          // 518 rec2 pairs

// 16-tap analysis low-pass (from reference)
constexpr float DLO[16] = {
    -0.0033824159510061256f, -0.0005421323317911481f, 0.03169508781149298f,
    0.007607487324917605f,  -0.1432942383508097f,    -0.061273359067658524f,
    0.4813596512583722f,     0.7771857517005235f,     0.36444189483533895f,
    -0.05194583810770904f,  -0.027219029917056003f,   0.049137179673607506f,
    0.003808752013890615f,  -0.01495225833704823f,   -0.0003029205147213668f,
    0.0018899503327594609f };

// ---------------- inline radix-select (run by last block of producer) ----------
// Reads hist via atomicExch (device-scope, cross-XCD safe) which also re-zeroes
// the bins for the next pass. 256 threads required.
__device__ void select_body(unsigned* hist, unsigned* prefix, unsigned* kArr,
                            float* lamArr, int nbins, int shift) {
    int t = threadIdx.x;
    int chunk = nbins >> 8;                 // 16 or 1
    __shared__ unsigned wsum[4];
    for (int s = 0; s < 2; ++s) {
        unsigned loc[16];
        unsigned* hs = hist + s * 4096 + t * chunk;
        unsigned csum = 0;
        for (int j = 0; j < chunk; ++j) { loc[j] = atomicExch(&hs[j], 0u); csum += loc[j]; }
        unsigned v = csum;
        int lane = t & 63, wv = t >> 6;
#pragma unroll
        for (int off = 1; off < 64; off <<= 1) {
            unsigned u = (unsigned)__shfl_up((int)v, off, 64);
            if (lane >= off) v += u;
        }
        if (lane == 63) wsum[wv] = v;
        __syncthreads();
        unsigned base = 0;
        for (int w2 = 0; w2 < wv; ++w2) base += wsum[w2];
        unsigned incl = base + v, excl = incl - csum;
        unsigned k = kArr[s];
        if (excl < k && incl >= k) {
            unsigned run = excl;
            for (int j = 0; j < chunk; ++j) {
                if (run < k && run + loc[j] >= k) {
                    unsigned digit = (unsigned)(t * chunk + j);
                    unsigned npref = prefix[s] | (digit << shift);
                    prefix[s] = npref;
                    kArr[s] = k - run;
                    if (shift == 0) {
                        float med = __uint_as_float(npref);
                        lamArr[s] = (med / 0.6745f) * sqrtf(2.0f * logf((float)L0));
                    }
                    break;
                }
                run += loc[j];
            }
        }
        __syncthreads();                    // wsum reuse for next s
    }
}

// last-block detection. NO __threadfence(): on gfx950 a device-scope fence
// emits an L2 writeback+invalidate (per-XCD L2s non-coherent) — measured
// +180us across 1806 blocks in R3 (dwt123 252us @ 346 GB/s). It is not
// needed here: ALL cross-block data consumed by select_body travels via
// device-scope atomics (hist atomicAdd -> atomicExch), and __syncthreads()
// drains vmcnt before s_barrier, so this block's hist atomics have
// completed at the coherence point before the done-counter increment.
__device__ bool i_am_last(unsigned* done, unsigned nBlocks) {
    __shared__ int amLast;
    __syncthreads();
    if (threadIdx.x == 0) {
        unsigned prev = atomicAdd(done, 1u);
        amLast = (prev == nBlocks - 1) ? 1 : 0;
    }
    __syncthreads();
    return amLast != 0;
}

// ---------------- moving average + residual (+ median state init) ---------------
__global__ void mavg_kernel(const float* __restrict__ x,
                            float* __restrict__ trend,
                            float* __restrict__ res,
                            unsigned* __restrict__ hist,
                            unsigned* __restrict__ prefix,
                            unsigned* __restrict__ kArr,
                            unsigned* __restrict__ done) {
    constexpr int NCH = TT / TCH;                 // 30
    int gid = blockIdx.x * blockDim.x + threadIdx.x;
    // fold init_median here (consumed by later kernels; stream order guarantees)
    if (gid < 8192) hist[gid] = 0;
    if (gid < 2) { prefix[gid] = 0; kArr[gid] = KMED; }
    if (gid < 3) done[gid] = 0;
    if (gid >= BB * NCH * NNN) return;
    int n    = gid % NNN;
    int rest = gid / NNN;
    int ch   = rest % NCH;
    int b    = rest / NCH;
    int t0   = ch * TCH;
    const float* xb = x + (size_t)b * TT * NNN + n;
    float sum = 0.f;
#pragma unroll
    for (int dt = -PP; dt <= PP; ++dt) {
        int tt = t0 + dt;
        tt = tt < 0 ? 0 : (tt >= TT ? TT - 1 : tt);
        sum += xb[(size_t)tt * NNN];
    }
    size_t base = (size_t)b * TT * NNN + (size_t)t0 * NNN + n;
    for (int i = 0; i < TCH; ++i) {
        int t = t0 + i;
        float tr = sum * (1.0f / (float)KK);
        size_t idx = base + (size_t)i * NNN;
        trend[idx] = tr;
        res[idx] = xb[(size_t)t * NNN] - tr;
        int tp = t + 1 + PP; if (tp > TT - 1) tp = TT - 1;
        int tm = t - PP;     if (tm < 0)      tm = 0;
        sum += xb[(size_t)tp * NNN] - xb[(size_t)tm * NNN];
    }
}

// ---------------- fused DWT levels 1+2+3 (+ hist pass 0 + inline select0) -------
__global__ void dwt123_kernel(const float* __restrict__ trend,
                              const float* __restrict__ res,
                              float* __restrict__ cd1,
                              float* __restrict__ cd2,
                              float* __restrict__ ca3,
                              float* __restrict__ cd3,
                              unsigned* __restrict__ hist,
                              unsigned* __restrict__ prefix,
                              unsigned* __restrict__ kArr,
                              float* __restrict__ lamArr,
                              unsigned* __restrict__ done) {
    int s = blockIdx.y;
    int C0 = blockIdx.x * NC3;
    const float* a0 = s ? res : trend;           // level-1 input, length L0
    __shared__ float s1[LEN1T];                  // ca1 tile
    __shared__ float s2[LEN2T];                  // ca2 tile
    __shared__ unsigned sh[4096];                // pass-0 histogram
    for (int b = threadIdx.x; b < 4096; b += 256) sh[b] = 0;
    __syncthreads();

    int T0 = 2 * C0 - 14;
    int S1 = 4 * C0 - 42; if (S1 < 0) S1 = 0;
    int E1 = 2 * (T0 + LEN2T) + 2; if (E1 > L1) E1 = L1;
    int len1 = E1 - S1;                          // <= LEN1T
    float* pcd1 = cd1 + (size_t)s * L1;

    // ---- stage 1: level-1 DWT from global trend/res -> s1 (ca) + global cd1 core
    int npair = (len1 + 1) / 2;
    for (int ip = threadIdx.x; ip < npair; ip += 256) {
        int i = 2 * ip;
        int o = S1 + i;                          // ca1/cd1 output index (pair o, o+1)
        float slo0, shi0, slo1, shi1;
        if (2 * o - 14 >= 0 && 2 * o + 3 < L0) {
            const float* p = a0 + 2 * o - 14;
            float v[18];
#pragma unroll
            for (int j = 0; j < 18; ++j) v[j] = p[j];
            slo0 = shi0 = slo1 = shi1 = 0.f;
#pragma unroll
            for (int j = 0; j < 16; ++j) {
                float h = (j & 1) ? DLO[15 - j] : -DLO[15 - j];
                slo0 = fmaf(DLO[j], v[15 - j], slo0);
                shi0 = fmaf(h,      v[15 - j], shi0);
                slo1 = fmaf(DLO[j], v[17 - j], slo1);
                shi1 = fmaf(h,      v[17 - j], shi1);
            }
        } else {
            float acc[2][2];
#pragma unroll
            for (int q = 0; q < 2; ++q) {
                int oo = o + q;
                float slo = 0.f, shi = 0.f;
                int bidx = 2 * oo + 1;
#pragma unroll
                for (int j = 0; j < 16; ++j) {
                    int idx = bidx - j;
                    if (idx < 0) idx = -1 - idx;
                    if (idx >= L0) idx = 2 * L0 - 1 - idx;
                    float v = a0[idx];
                    slo = fmaf(DLO[j], v, slo);
                    float h = (j & 1) ? DLO[15 - j] : -DLO[15 - j];
                    shi = fmaf(h, v, shi);
                }
                acc[q][0] = slo; acc[q][1] = shi;
            }
            slo0 = acc[0][0]; shi0 = acc[0][1];
            slo1 = acc[1][0]; shi1 = acc[1][1];
        }
        s1[i] = slo0;
        if (o >= 4 * C0 && o < 4 * C0 + 4 * NC3) {
            pcd1[o] = shi0;
            atomicAdd(&sh[__float_as_uint(fabsf(shi0)) >> 20], 1u);
        }
        if (i + 1 < len1) {
            s1[i + 1] = slo1;
            int o1 = o + 1;
            if (o1 >= 4 * C0 && o1 < 4 * C0 + 4 * NC3) {
                pcd1[o1] = shi1;
                atomicAdd(&sh[__float_as_uint(fabsf(shi1)) >> 20], 1u);
            }
        }
    }
    __syncthreads();

    // flush pass-0 histogram (global-atomic latency overlaps stage 2)
    for (int b = threadIdx.x; b < 4096; b += 256) {
        unsigned c = sh[b];
        if (c) atomicAdd(&hist[s * 4096 + b], c);
    }

    // ---- stage 2: level-2 DWT from s1 -> s2 (ca2) + global cd2 core
    float* pcd2 = cd2 + (size_t)s * L2;
    for (int i = threadIdx.x; i < LEN2T; i += 256) {
        int e = T0 + i;
        if (e < 0 || e >= L2) continue;
        int base = 2 * e + 1;
        float slo = 0.f, shi = 0.f;
#pragma unroll
        for (int j = 0; j < 16; ++j) {
            int idx = base - j;
            if (idx < 0) idx = -1 - idx;
            if (idx >= L1) idx = 2 * L1 - 1 - idx;
            float v = s1[idx - S1];
            slo = fmaf(DLO[j], v, slo);
            float h = (j & 1) ? DLO[15 - j] : -DLO[15 - j];
            shi = fmaf(h, v, shi);
        }
        s2[i] = slo;
        if (e >= 2 * C0 && e < 2 * C0 + 2 * NC3) pcd2[e] = shi;
    }
    __syncthreads();
    // reflection fill for out-of-range ca2 tile slots (edges only)
    for (int i = threadIdx.x; i < LEN2T; i += 256) {
        int e = T0 + i;
        if (e < 0)        s2[i] = s2[(-1 - e) - T0];
        else if (e >= L2) s2[i] = s2[(2 * L2 - 1 - e) - T0];
    }
    __syncthreads();
    // ---- stage 3: level-3 DWT from s2
    float* pca3 = ca3 + (size_t)s * L3;
    float* pcd3 = cd3 + (size_t)s * L3;
    for (int i = threadIdx.x; i < NC3; i += 256) {
        int o = C0 + i;
        if (o >= L3) break;
        int b2 = 2 * o + 1 - T0;
        float slo = 0.f, shi = 0.f;
#pragma unroll
        for (int j = 0; j < 16; ++j) {
            float v = s2[b2 - j];
            slo = fmaf(DLO[j], v, slo);
            float h = (j & 1) ? DLO[15 - j] : -DLO[15 - j];
            shi = fmaf(h, v, shi);
        }
        pca3[o] = slo;
        pcd3[o] = shi;
    }

    // ---- last block runs select pass 0 (top 12 bits)
    if (i_am_last(done + 0, gridDim.x * gridDim.y))
        select_body(hist, prefix, kArr, lamArr, 4096, 20);
}

// ---------------- soft threshold ----------------
__device__ __forceinline__ float sthr(float d, float lam, float alam) {
    float ad = fabsf(d);
    return (ad >= lam) ? copysignf(ad - alam, d) : 0.f;
}

// ---------------- fused 3-level IDWT + final outputs ----------------
__global__ void idwt_fused(const float* __restrict__ ca3,
                           const float* __restrict__ cd3,
                           const float* __restrict__ cd2,
                           const float* __restrict__ cd1,
                           const float* __restrict__ trend,
                           const float* __restrict__ res,
                           float* __restrict__ out,
                           const float* __restrict__ lamArr) {
    int s = blockIdx.y;
    int F0 = blockIdx.x * NF0;
    float lam = lamArr[s], alam = AA * lam;
    const float* pa3 = ca3 + (size_t)s * L3;
    const float* pd3 = cd3 + (size_t)s * L3;
    const float* pd2 = cd2 + (size_t)s * L2;
    const float* pd1 = cd1 + (size_t)s * L1;
    __shared__ float r2[N2T + 1];
    __shared__ float r1[N1T];
    int A1 = F0 >> 1, A2 = F0 >> 2, Q3 = F0 >> 3;
    // stage rec2 tile from ca3/cd3 (level 3 -> 2)
    for (int i = threadIdx.x; i < NQ3; i += 256) {
        int q3 = Q3 + i;
        float a0 = 0.f, a1 = 0.f;
#pragma unroll
        for (int p = 0; p < 8; ++p) {
            int idx = q3 + p; if (idx > L3 - 1) idx = L3 - 1;
            float a = pa3[idx];
            float d = sthr(pd3[idx], lam, alam);
            a0 = fmaf(a, DLO[2 * p + 1], a0);
            a0 = fmaf(d, DLO[14 - 2 * p], a0);
            a1 = fmaf(a, DLO[2 * p], a1);
            a1 = fmaf(d, -DLO[15 - 2 * p], a1);
        }
        r2[2 * i] = a0; r2[2 * i + 1] = a1;
    }
    __syncthreads();
    // stage rec1 tile from rec2(LDS) + cd2(global) (level 2 -> 1)
    for (int i = threadIdx.x; i < N1T / 2; i += 256) {
        int q2 = A2 + i;
        float a0 = 0.f, a1 = 0.f;
#pragma unroll
        for (int p = 0; p < 8; ++p) {
            float a = r2[i + p];
            int idx = q2 + p; if (idx > L2 - 1) idx = L2 - 1;
            float d = sthr(pd2[idx], lam, alam);
            a0 = fmaf(a, DLO[2 * p + 1], a0);
            a0 = fmaf(d, DLO[14 - 2 * p], a0);
            a1 = fmaf(a, DLO[2 * p], a1);
            a1 = fmaf(d, -DLO[15 - 2 * p], a1);
        }
        r1[2 * i] = a0; r1[2 * i + 1] = a1;
    }
    __syncthreads();
    // final level from rec1(LDS) + cd1(global): 4 outputs/thread, float4 I/O
    const float* orig = s ? res : trend;
    float* o_diff = out + (size_t)(2 * s) * L0;
    float* o_nn   = out + (size_t)(2 * s + 1) * L0;
    for (int i = threadIdx.x; i < NF0 / 4; i += 256) {
        int ii = 2 * i;                      // r1-local index of first q1
        int q1 = A1 + ii;
        int r0 = 2 * q1;                     // multiple of 4; L0 % 4 == 0
        if (r0 >= L0) break;
        float d[9];
#pragma unroll
        for (int p = 0; p < 9; ++p) {
            int idx = q1 + p; if (idx > L1 - 1) idx = L1 - 1;
            d[p] = sthr(pd1[idx], lam, alam);
        }
        float a0 = 0.f, a1 = 0.f, b0 = 0.f, b1 = 0.f;
#pragma unroll
        for (int p = 0; p < 8; ++p) {
            float a  = r1[ii + p];
            float ab = r1[ii + 1 + p];
            a0 = fmaf(a,      DLO[2 * p + 1], a0);
            a0 = fmaf(d[p],   DLO[14 - 2 * p], a0);
            a1 = fmaf(a,      DLO[2 * p], a1);
            a1 = fmaf(d[p],  -DLO[15 - 2 * p], a1);
            b0 = fmaf(ab,     DLO[2 * p + 1], b0);
            b0 = fmaf(d[p+1], DLO[14 - 2 * p], b0);
            b1 = fmaf(ab,     DLO[2 * p], b1);
            b1 = fmaf(d[p+1],-DLO[15 - 2 * p], b1);
        }
        float4 o4 = *(const float4*)(orig + r0);
        float4 nn; nn.x = a0; nn.y = a1; nn.z = b0; nn.w = b1;
        float4 df; df.x = o4.x - a0; df.y = o4.y - a1; df.z = o4.z - b0; df.w = o4.w - b1;
        *(float4*)(o_nn + r0)   = nn;
        *(float4*)(o_diff + r0) = df;
    }
}

// pass 1: contiguous per-block chunks; filter on 12-bit prefix, histogram
// next 12 bits, compact survivors into the block's PRIVATE cand region.
// Last block runs select pass 1 inline.
__global__ void hist1_kernel(const float* __restrict__ d,
                             unsigned* __restrict__ hist,
                             unsigned* __restrict__ prefix,
                             unsigned* __restrict__ cand,
                             unsigned* __restrict__ bcnt,
                             unsigned* __restrict__ kArr,
                             float* __restrict__ lamArr,
                             unsigned* __restrict__ done) {
    int s = blockIdx.y;
    int blk = blockIdx.x;
    const float* ds = d + (size_t)s * L1;
    unsigned* cs = cand + (size_t)s * CANDSZ + (size_t)blk * CH;
    __shared__ unsigned sh[4096];
    __shared__ unsigned slocal;
    for (int b = threadIdx.x; b < 4096; b += 256) sh[b] = 0;
    if (threadIdx.x == 0) slocal = 0;
    __syncthreads();
    unsigned pref = prefix[s] >> 20;
    int i0 = blk * CH;
    int i1 = i0 + CH; if (i1 > L1) i1 = L1;
    for (int i = i0 + threadIdx.x; i < i1; i += 256) {
        unsigned u = __float_as_uint(fabsf(ds[i]));
        if ((u >> 20) == pref) {
            atomicAdd(&sh[(u >> 8) & 0xFFFu], 1u);
            unsigned pos = atomicAdd(&slocal, 1u);
            cs[pos] = u;
        }
    }
    __syncthreads();
    if (threadIdx.x == 0) bcnt[s * NH1B + blk] = slocal;
    for (int b = threadIdx.x; b < 4096; b += 256) {
        unsigned c = sh[b];
        if (c) atomicAdd(&hist[s * 4096 + b], c);
    }
    if (i_am_last(done + 1, gridDim.x * gridDim.y))
        select_body(hist, prefix, kArr, lamArr, 4096, 8);
}

// pass 2: last 8 bits over the compacted per-block candidate lists (tiny).
// Last block runs final select + lambda computation inline.
__global__ void hist2_kernel(const unsigned* __restrict__ cand,
                             unsigned* __restrict__ hist,
                             unsigned* __restrict__ prefix,
                             const unsigned* __restrict__ bcnt,
                             unsigned* __restrict__ kArr,
                             float* __restrict__ lamArr,
                             unsigned* __restrict__ done) {
    int s = blockIdx.y;
    int blk = blockIdx.x;
    const unsigned* cs = cand + (size_t)s * CANDSZ + (size_t)blk * CH;
    __shared__ unsigned sh[256];
    sh[threadIdx.x] = 0;
    __syncthreads();
    unsigned pref = prefix[s] >> 8;
    unsigned n = bcnt[s * NH1B + blk];
    for (unsigned i = threadIdx.x; i < n; i += 256) {
        unsigned u = cs[i];
        if ((u >> 8) == pref) atomicAdd(&sh[u & 0xFFu], 1u);
    }
    __syncthreads();
    unsigned c = sh[threadIdx.x];
    if (c) atomicAdd(&hist[s * 4096 + threadIdx.x], c);
    if (i_am_last(done + 2, gridDim.x * gridDim.y))
        select_body(hist, prefix, kArr, lamArr, 256, 0);
}

extern "C" void kernel_launch(void* const* d_in, const int* in_sizes, int n_in,
                              void* d_out, int out_size, void* d_ws, size_t ws_size,
                              hipStream_t stream) {
    const float* x = (const float*)d_in[0];
    float* out = (float*)d_out;
    float* w = (float*)d_ws;

    float* trend = w;
    float* res   = w + (size_t)L0;
    float* cd1   = w + 2 * (size_t)L0;
    float* cd2   = cd1 + 2 * (size_t)L1;
    float* ca3   = cd2 + 2 * (size_t)L2;
    float* cd3   = ca3 + 2 * (size_t)L3;
    unsigned* cand   = (unsigned*)(cd3 + 2 * (size_t)L3);
    unsigned* hist   = cand + 2 * (size_t)CANDSZ;
    unsigned* prefix = hist + 8192;
    unsigned* kArr   = prefix + 2;
    float*    lamArr = (float*)(kArr + 2);
    unsigned* bcnt   = (unsigned*)(lamArr + 2);   // 2 * NH1B entries
    unsigned* done   = bcnt + 2 * NH1B;           // 3 done-counters

    dim3 b256(256);

    {
        int nthreads = BB * (TT / TCH) * NNN;
        mavg_kernel<<<(nthreads + 255) / 256, b256, 0, stream>>>(
            x, trend, res, hist, prefix, kArr, done);
    }
    // fused 3-level decomposition + pass-0 histogram + inline select0
    dwt123_kernel<<<dim3((L3 + NC3 - 1) / NC3, 2), b256, 0, stream>>>(
        trend, res, cd1, cd2, ca3, cd3, hist, prefix, kArr, lamArr, done);
    // pass-1 histogram + compaction + inline select1
    hist1_kernel<<<dim3(NH1B, 2), b256, 0, stream>>>(
        cd1, hist, prefix, cand, bcnt, kArr, lamArr, done);
    // pass-2 histogram over candidates + inline select2 (computes lambda)
    hist2_kernel<<<dim3(NH1B, 2), b256, 0, stream>>>(
        cand, hist, prefix, bcnt, kArr, lamArr, done);
    // fused 3-level reconstruction + output
    idwt_fused<<<dim3((L0 + NF0 - 1) / NF0, 2), b256, 0, stream>>>(
        ca3, cd3, cd2, cd1, trend, res, out, lamArr);
}

// Round 5
// 321.988 us; speedup vs baseline: 1.8317x; 1.0222x over previous
//
#include <hip/hip_runtime.h>
#include <math.h>

#define BB 32
#define TT 720
#define NNN 321
#define KK 25
#define PP 12
#define TCH 24   // T-chunk per thread in mavg; 720 = 30 * 24

constexpr int L0 = BB * TT * NNN;          // 7,395,840
constexpr int L1 = (L0 + 15) / 2;          // 3,697,927
constexpr int L2 = (L1 + 15) / 2;          // 1,848,971
constexpr int L3 = (L2 + 15) / 2;          // 924,493
constexpr unsigned KMED = (unsigned)((L1 - 1) / 2 + 1);
constexpr float AA = 0.85f;

// median pass-1 compaction geometry: 512 blocks, contiguous chunks
constexpr int NH1B = 512;                       // hist1 blocks per signal
constexpr int CH   = (L1 + NH1B - 1) / NH1B;    // 7223 elements/block
constexpr int CANDSZ = NH1B * CH;               // per-signal cand region

// fused-kernel tile params
#define NC3 1024                            // ca3 outputs per block in dwt123
constexpr int LEN2T = 2 * NC3 + 32;         // ca2 tile slots (raw T0 = 2*C0-14)
constexpr int LEN1T = 4 * NC3 + 80;         // ca1 tile slots (= len1 max); >= 4096 (hist alias)
#define NF0 4096                            // final outputs per block in idwt_fused (div by 8)
constexpr int N1T = NF0 / 2 + 8;            // 2056 rec1 tile
constexpr int N2T = N1T / 2 + 7;            // 1035 rec2 tile
constexpr int NQ3 = (N2T + 1) / 2;          // 518 rec2 pairs

// 16-tap analysis low-pass (from reference)
constexpr float DLO[16] = {
    -0.0033824159510061256f, -0.0005421323317911481f, 0.03169508781149298f,
    0.007607487324917605f,  -0.1432942383508097f,    -0.061273359067658524f,
    0.4813596512583722f,     0.7771857517005235f,     0.36444189483533895f,
    -0.05194583810770904f,  -0.027219029917056003f,   0.049137179673607506f,
    0.003808752013890615f,  -0.01495225833704823f,   -0.0003029205147213668f,
    0.0018899503327594609f };

// ---------------- inline radix-select (run by last block of producer) ----------
// Reads hist via atomicExch (device-scope, cross-XCD safe) which also re-zeroes
// the bins for the next pass. 256 threads required.
__device__ void select_body(unsigned* hist, unsigned* prefix, unsigned* kArr,
                            float* lamArr, int nbins, int shift) {
    int t = threadIdx.x;
    int chunk = nbins >> 8;                 // 16 or 1
    __shared__ unsigned wsum[4];
    for (int s = 0; s < 2; ++s) {
        unsigned loc[16];
        unsigned* hs = hist + s * 4096 + t * chunk;
        unsigned csum = 0;
        for (int j = 0; j < chunk; ++j) { loc[j] = atomicExch(&hs[j], 0u); csum += loc[j]; }
        unsigned v = csum;
        int lane = t & 63, wv = t >> 6;
#pragma unroll
        for (int off = 1; off < 64; off <<= 1) {
            unsigned u = (unsigned)__shfl_up((int)v, off, 64);
            if (lane >= off) v += u;
        }
        if (lane == 63) wsum[wv] = v;
        __syncthreads();
        unsigned base = 0;
        for (int w2 = 0; w2 < wv; ++w2) base += wsum[w2];
        unsigned incl = base + v, excl = incl - csum;
        unsigned k = kArr[s];
        if (excl < k && incl >= k) {
            unsigned run = excl;
            for (int j = 0; j < chunk; ++j) {
                if (run < k && run + loc[j] >= k) {
                    unsigned digit = (unsigned)(t * chunk + j);
                    unsigned npref = prefix[s] | (digit << shift);
                    prefix[s] = npref;
                    kArr[s] = k - run;
                    if (shift == 0) {
                        float med = __uint_as_float(npref);
                        lamArr[s] = (med / 0.6745f) * sqrtf(2.0f * logf((float)L0));
                    }
                    break;
                }
                run += loc[j];
            }
        }
        __syncthreads();                    // wsum reuse for next s
    }
}

// last-block detection. NO __threadfence(): on gfx950 a device-scope fence
// emits an L2 writeback+invalidate (per-XCD L2s non-coherent) — measured
// +180us across 1806 blocks in R3 (dwt123 252us @ 346 GB/s). It is not
// needed here: ALL cross-block data consumed by select_body travels via
// device-scope atomics (hist atomicAdd -> atomicExch), and __syncthreads()
// drains vmcnt before s_barrier, so this block's hist atomics have
// completed at the coherence point before the done-counter increment.
__device__ bool i_am_last(unsigned* done, unsigned nBlocks) {
    __shared__ int amLast;
    __syncthreads();
    if (threadIdx.x == 0) {
        unsigned prev = atomicAdd(done, 1u);
        amLast = (prev == nBlocks - 1) ? 1 : 0;
    }
    __syncthreads();
    return amLast != 0;
}

// ---------------- moving average + residual (+ median state init) ---------------
__global__ void mavg_kernel(const float* __restrict__ x,
                            float* __restrict__ trend,
                            float* __restrict__ res,
                            unsigned* __restrict__ hist,
                            unsigned* __restrict__ prefix,
                            unsigned* __restrict__ kArr,
                            unsigned* __restrict__ done) {
    constexpr int NCH = TT / TCH;                 // 30
    int gid = blockIdx.x * blockDim.x + threadIdx.x;
    // fold init_median here (consumed by later kernels; stream order guarantees)
    if (gid < 8192) hist[gid] = 0;
    if (gid < 2) { prefix[gid] = 0; kArr[gid] = KMED; }
    if (gid < 3) done[gid] = 0;
    if (gid >= BB * NCH * NNN) return;
    int n    = gid % NNN;
    int rest = gid / NNN;
    int ch   = rest % NCH;
    int b    = rest / NCH;
    int t0   = ch * TCH;
    const float* xb = x + (size_t)b * TT * NNN + n;
    float sum = 0.f;
#pragma unroll
    for (int dt = -PP; dt <= PP; ++dt) {
        int tt = t0 + dt;
        tt = tt < 0 ? 0 : (tt >= TT ? TT - 1 : tt);
        sum += xb[(size_t)tt * NNN];
    }
    size_t base = (size_t)b * TT * NNN + (size_t)t0 * NNN + n;
    for (int i = 0; i < TCH; ++i) {
        int t = t0 + i;
        float tr = sum * (1.0f / (float)KK);
        size_t idx = base + (size_t)i * NNN;
        trend[idx] = tr;
        res[idx] = xb[(size_t)t * NNN] - tr;
        int tp = t + 1 + PP; if (tp > TT - 1) tp = TT - 1;
        int tm = t - PP;     if (tm < 0)      tm = 0;
        sum += xb[(size_t)tp * NNN] - xb[(size_t)tm * NNN];
    }
}

// ---------------- fused DWT levels 1+2+3 (+ hist pass 0 + inline select0) -------
// LDS plan (25.0 KB -> 6 blocks/CU, was 41.5 KB -> 3):
//   s1[LEN1T] holds the ca1 tile for stages 1-2, then is DEAD; the 4096-bin
//   pass-0 histogram `sh` ALIASES s1's storage. Histogram is accumulated in
//   the stage-3 phase by re-reading this block's own cd1 core from global
//   (just written; same-CU L1 / same-XCD L2 hot; __syncthreads' vmcnt drain
//   makes the writes visible intra-block).
__global__ void dwt123_kernel(const float* __restrict__ trend,
                              const float* __restrict__ res,
                              float* __restrict__ cd1,
                              float* __restrict__ cd2,
                              float* __restrict__ ca3,
                              float* __restrict__ cd3,
                              unsigned* __restrict__ hist,
                              unsigned* __restrict__ prefix,
                              unsigned* __restrict__ kArr,
                              float* __restrict__ lamArr,
                              unsigned* __restrict__ done) {
    int s = blockIdx.y;
    int C0 = blockIdx.x * NC3;
    const float* a0 = s ? res : trend;           // level-1 input, length L0
    __shared__ float s1[LEN1T];                  // ca1 tile, later aliased as hist
    __shared__ float s2[LEN2T];                  // ca2 tile
    unsigned* sh = (unsigned*)s1;                // 4096 bins fit in LEN1T*4 bytes

    int T0 = 2 * C0 - 14;
    int S1 = 4 * C0 - 42; if (S1 < 0) S1 = 0;
    int E1 = 2 * (T0 + LEN2T) + 2; if (E1 > L1) E1 = L1;
    int len1 = E1 - S1;                          // <= LEN1T
    float* pcd1 = cd1 + (size_t)s * L1;

    // ---- stage 1: level-1 DWT from global trend/res -> s1 (ca) + global cd1 core
    int npair = (len1 + 1) / 2;
    for (int ip = threadIdx.x; ip < npair; ip += 256) {
        int i = 2 * ip;
        int o = S1 + i;                          // ca1/cd1 output index (pair o, o+1)
        float slo0, shi0, slo1, shi1;
        if (2 * o - 14 >= 0 && 2 * o + 3 < L0) {
            const float* p = a0 + 2 * o - 14;
            float v[18];
#pragma unroll
            for (int j = 0; j < 18; ++j) v[j] = p[j];
            slo0 = shi0 = slo1 = shi1 = 0.f;
#pragma unroll
            for (int j = 0; j < 16; ++j) {
                float h = (j & 1) ? DLO[15 - j] : -DLO[15 - j];
                slo0 = fmaf(DLO[j], v[15 - j], slo0);
                shi0 = fmaf(h,      v[15 - j], shi0);
                slo1 = fmaf(DLO[j], v[17 - j], slo1);
                shi1 = fmaf(h,      v[17 - j], shi1);
            }
        } else {
            float acc[2][2];
#pragma unroll
            for (int q = 0; q < 2; ++q) {
                int oo = o + q;
                float slo = 0.f, shi = 0.f;
                int bidx = 2 * oo + 1;
#pragma unroll
                for (int j = 0; j < 16; ++j) {
                    int idx = bidx - j;
                    if (idx < 0) idx = -1 - idx;
                    if (idx >= L0) idx = 2 * L0 - 1 - idx;
                    float v = a0[idx];
                    slo = fmaf(DLO[j], v, slo);
                    float h = (j & 1) ? DLO[15 - j] : -DLO[15 - j];
                    shi = fmaf(h, v, shi);
                }
                acc[q][0] = slo; acc[q][1] = shi;
            }
            slo0 = acc[0][0]; shi0 = acc[0][1];
            slo1 = acc[1][0]; shi1 = acc[1][1];
        }
        s1[i] = slo0;
        if (o >= 4 * C0 && o < 4 * C0 + 4 * NC3) pcd1[o] = shi0;
        if (i + 1 < len1) {
            s1[i + 1] = slo1;
            int o1 = o + 1;
            if (o1 >= 4 * C0 && o1 < 4 * C0 + 4 * NC3) pcd1[o1] = shi1;
        }
    }
    __syncthreads();

    // ---- stage 2: level-2 DWT from s1 -> s2 (ca2) + global cd2 core
    float* pcd2 = cd2 + (size_t)s * L2;
    for (int i = threadIdx.x; i < LEN2T; i += 256) {
        int e = T0 + i;
        if (e < 0 || e >= L2) continue;
        int base = 2 * e + 1;
        float slo = 0.f, shi = 0.f;
#pragma unroll
        for (int j = 0; j < 16; ++j) {
            int idx = base - j;
            if (idx < 0) idx = -1 - idx;
            if (idx >= L1) idx = 2 * L1 - 1 - idx;
            float v = s1[idx - S1];
            slo = fmaf(DLO[j], v, slo);
            float h = (j & 1) ? DLO[15 - j] : -DLO[15 - j];
            shi = fmaf(h, v, shi);
        }
        s2[i] = slo;
        if (e >= 2 * C0 && e < 2 * C0 + 2 * NC3) pcd2[e] = shi;
    }
    __syncthreads();                             // s1 consumption complete; s1 dead

    // reflection fill for out-of-range ca2 tile slots (edges only) + zero hist
    for (int i = threadIdx.x; i < LEN2T; i += 256) {
        int e = T0 + i;
        if (e < 0)        s2[i] = s2[(-1 - e) - T0];
        else if (e >= L2) s2[i] = s2[(2 * L2 - 1 - e) - T0];
    }
    for (int b = threadIdx.x; b < 4096; b += 256) sh[b] = 0;
    __syncthreads();

    // ---- stage 3: level-3 DWT from s2 (+ pass-0 histogram of own cd1 core)
    float* pca3 = ca3 + (size_t)s * L3;
    float* pcd3 = cd3 + (size_t)s * L3;
    for (int i = threadIdx.x; i < NC3; i += 256) {
        int o = C0 + i;
        if (o >= L3) break;
        int b2 = 2 * o + 1 - T0;
        float slo = 0.f, shi = 0.f;
#pragma unroll
        for (int j = 0; j < 16; ++j) {
            float v = s2[b2 - j];
            slo = fmaf(DLO[j], v, slo);
            float h = (j & 1) ? DLO[15 - j] : -DLO[15 - j];
            shi = fmaf(h, v, shi);
        }
        pca3[o] = slo;
        pcd3[o] = shi;
    }
    {   // histogram: re-read this block's cd1 core (L1/L2-hot, coalesced)
        int h0 = 4 * C0;
        int h1 = h0 + 4 * NC3; if (h1 > L1) h1 = L1;
        for (int i = h0 + threadIdx.x; i < h1; i += 256) {
            unsigned u = __float_as_uint(fabsf(pcd1[i]));
            atomicAdd(&sh[u >> 20], 1u);
        }
    }
    __syncthreads();

    // flush pass-0 histogram to global
    for (int b = threadIdx.x; b < 4096; b += 256) {
        unsigned c = sh[b];
        if (c) atomicAdd(&hist[s * 4096 + b], c);
    }

    // ---- last block runs select pass 0 (top 12 bits)
    if (i_am_last(done + 0, gridDim.x * gridDim.y))
        select_body(hist, prefix, kArr, lamArr, 4096, 20);
}

// ---------------- soft threshold ----------------
__device__ __forceinline__ float sthr(float d, float lam, float alam) {
    float ad = fabsf(d);
    return (ad >= lam) ? copysignf(ad - alam, d) : 0.f;
}

// ---------------- fused 3-level IDWT + final outputs ----------------
__global__ void idwt_fused(const float* __restrict__ ca3,
                           const float* __restrict__ cd3,
                           const float* __restrict__ cd2,
                           const float* __restrict__ cd1,
                           const float* __restrict__ trend,
                           const float* __restrict__ res,
                           float* __restrict__ out,
                           const float* __restrict__ lamArr) {
    int s = blockIdx.y;
    int F0 = blockIdx.x * NF0;
    float lam = lamArr[s], alam = AA * lam;
    const float* pa3 = ca3 + (size_t)s * L3;
    const float* pd3 = cd3 + (size_t)s * L3;
    const float* pd2 = cd2 + (size_t)s * L2;
    const float* pd1 = cd1 + (size_t)s * L1;
    __shared__ float r2[N2T + 1];
    __shared__ float r1[N1T];
    int A1 = F0 >> 1, A2 = F0 >> 2, Q3 = F0 >> 3;
    // stage rec2 tile from ca3/cd3 (level 3 -> 2)
    for (int i = threadIdx.x; i < NQ3; i += 256) {
        int q3 = Q3 + i;
        float a0 = 0.f, a1 = 0.f;
#pragma unroll
        for (int p = 0; p < 8; ++p) {
            int idx = q3 + p; if (idx > L3 - 1) idx = L3 - 1;
            float a = pa3[idx];
            float d = sthr(pd3[idx], lam, alam);
            a0 = fmaf(a, DLO[2 * p + 1], a0);
            a0 = fmaf(d, DLO[14 - 2 * p], a0);
            a1 = fmaf(a, DLO[2 * p], a1);
            a1 = fmaf(d, -DLO[15 - 2 * p], a1);
        }
        r2[2 * i] = a0; r2[2 * i + 1] = a1;
    }
    __syncthreads();
    // stage rec1 tile from rec2(LDS) + cd2(global) (level 2 -> 1)
    for (int i = threadIdx.x; i < N1T / 2; i += 256) {
        int q2 = A2 + i;
        float a0 = 0.f, a1 = 0.f;
#pragma unroll
        for (int p = 0; p < 8; ++p) {
            float a = r2[i + p];
            int idx = q2 + p; if (idx > L2 - 1) idx = L2 - 1;
            float d = sthr(pd2[idx], lam, alam);
            a0 = fmaf(a, DLO[2 * p + 1], a0);
            a0 = fmaf(d, DLO[14 - 2 * p], a0);
            a1 = fmaf(a, DLO[2 * p], a1);
            a1 = fmaf(d, -DLO[15 - 2 * p], a1);
        }
        r1[2 * i] = a0; r1[2 * i + 1] = a1;
    }
    __syncthreads();
    // final level from rec1(LDS) + cd1(global): 4 outputs/thread, float4 I/O
    const float* orig = s ? res : trend;
    float* o_diff = out + (size_t)(2 * s) * L0;
    float* o_nn   = out + (size_t)(2 * s + 1) * L0;
    for (int i = threadIdx.x; i < NF0 / 4; i += 256) {
        int ii = 2 * i;                      // r1-local index of first q1
        int q1 = A1 + ii;
        int r0 = 2 * q1;                     // multiple of 4; L0 % 4 == 0
        if (r0 >= L0) break;
        float d[9];
#pragma unroll
        for (int p = 0; p < 9; ++p) {
            int idx = q1 + p; if (idx > L1 - 1) idx = L1 - 1;
            d[p] = sthr(pd1[idx], lam, alam);
        }
        float a0 = 0.f, a1 = 0.f, b0 = 0.f, b1 = 0.f;
#pragma unroll
        for (int p = 0; p < 8; ++p) {
            float a  = r1[ii + p];
            float ab = r1[ii + 1 + p];
            a0 = fmaf(a,      DLO[2 * p + 1], a0);
            a0 = fmaf(d[p],   DLO[14 - 2 * p], a0);
            a1 = fmaf(a,      DLO[2 * p], a1);
            a1 = fmaf(d[p],  -DLO[15 - 2 * p], a1);
            b0 = fmaf(ab,     DLO[2 * p + 1], b0);
            b0 = fmaf(d[p+1], DLO[14 - 2 * p], b0);
            b1 = fmaf(ab,     DLO[2 * p], b1);
            b1 = fmaf(d[p+1],-DLO[15 - 2 * p], b1);
        }
        float4 o4 = *(const float4*)(orig + r0);
        float4 nn; nn.x = a0; nn.y = a1; nn.z = b0; nn.w = b1;
        float4 df; df.x = o4.x - a0; df.y = o4.y - a1; df.z = o4.z - b0; df.w = o4.w - b1;
        *(float4*)(o_nn + r0)   = nn;
        *(float4*)(o_diff + r0) = df;
    }
}

// pass 1: contiguous per-block chunks; filter on 12-bit prefix, histogram
// next 12 bits, compact survivors into the block's PRIVATE cand region.
// Last block runs select pass 1 inline.
__global__ void hist1_kernel(const float* __restrict__ d,
                             unsigned* __restrict__ hist,
                             unsigned* __restrict__ prefix,
                             unsigned* __restrict__ cand,
                             unsigned* __restrict__ bcnt,
                             unsigned* __restrict__ kArr,
                             float* __restrict__ lamArr,
                             unsigned* __restrict__ done) {
    int s = blockIdx.y;
    int blk = blockIdx.x;
    const float* ds = d + (size_t)s * L1;
    unsigned* cs = cand + (size_t)s * CANDSZ + (size_t)blk * CH;
    __shared__ unsigned sh[4096];
    __shared__ unsigned slocal;
    for (int b = threadIdx.x; b < 4096; b += 256) sh[b] = 0;
    if (threadIdx.x == 0) slocal = 0;
    __syncthreads();
    unsigned pref = prefix[s] >> 20;
    int i0 = blk * CH;
    int i1 = i0 + CH; if (i1 > L1) i1 = L1;
    for (int i = i0 + threadIdx.x; i < i1; i += 256) {
        unsigned u = __float_as_uint(fabsf(ds[i]));
        if ((u >> 20) == pref) {
            atomicAdd(&sh[(u >> 8) & 0xFFFu], 1u);
            unsigned pos = atomicAdd(&slocal, 1u);
            cs[pos] = u;
        }
    }
    __syncthreads();
    if (threadIdx.x == 0) bcnt[s * NH1B + blk] = slocal;
    for (int b = threadIdx.x; b < 4096; b += 256) {
        unsigned c = sh[b];
        if (c) atomicAdd(&hist[s * 4096 + b], c);
    }
    if (i_am_last(done + 1, gridDim.x * gridDim.y))
        select_body(hist, prefix, kArr, lamArr, 4096, 8);
}

// pass 2: last 8 bits over the compacted per-block candidate lists (tiny).
// Last block runs final select + lambda computation inline.
__global__ void hist2_kernel(const unsigned* __restrict__ cand,
                             unsigned* __restrict__ hist,
                             unsigned* __restrict__ prefix,
                             const unsigned* __restrict__ bcnt,
                             unsigned* __restrict__ kArr,
                             float* __restrict__ lamArr,
                             unsigned* __restrict__ done) {
    int s = blockIdx.y;
    int blk = blockIdx.x;
    const unsigned* cs = cand + (size_t)s * CANDSZ + (size_t)blk * CH;
    __shared__ unsigned sh[256];
    sh[threadIdx.x] = 0;
    __syncthreads();
    unsigned pref = prefix[s] >> 8;
    unsigned n = bcnt[s * NH1B + blk];
    for (unsigned i = threadIdx.x; i < n; i += 256) {
        unsigned u = cs[i];
        if ((u >> 8) == pref) atomicAdd(&sh[u & 0xFFu], 1u);
    }
    __syncthreads();
    unsigned c = sh[threadIdx.x];
    if (c) atomicAdd(&hist[s * 4096 + threadIdx.x], c);
    if (i_am_last(done + 2, gridDim.x * gridDim.y))
        select_body(hist, prefix, kArr, lamArr, 256, 0);
}

extern "C" void kernel_launch(void* const* d_in, const int* in_sizes, int n_in,
                              void* d_out, int out_size, void* d_ws, size_t ws_size,
                              hipStream_t stream) {
    const float* x = (const float*)d_in[0];
    float* out = (float*)d_out;
    float* w = (float*)d_ws;

    float* trend = w;
    float* res   = w + (size_t)L0;
    float* cd1   = w + 2 * (size_t)L0;
    float* cd2   = cd1 + 2 * (size_t)L1;
    float* ca3   = cd2 + 2 * (size_t)L2;
    float* cd3   = ca3 + 2 * (size_t)L3;
    unsigned* cand   = (unsigned*)(cd3 + 2 * (size_t)L3);
    unsigned* hist   = cand + 2 * (size_t)CANDSZ;
    unsigned* prefix = hist + 8192;
    unsigned* kArr   = prefix + 2;
    float*    lamArr = (float*)(kArr + 2);
    unsigned* bcnt   = (unsigned*)(lamArr + 2);   // 2 * NH1B entries
    unsigned* done   = bcnt + 2 * NH1B;           // 3 done-counters

    dim3 b256(256);

    {
        int nthreads = BB * (TT / TCH) * NNN;
        mavg_kernel<<<(nthreads + 255) / 256, b256, 0, stream>>>(
            x, trend, res, hist, prefix, kArr, done);
    }
    // fused 3-level decomposition + pass-0 histogram + inline select0
    dwt123_kernel<<<dim3((L3 + NC3 - 1) / NC3, 2), b256, 0, stream>>>(
        trend, res, cd1, cd2, ca3, cd3, hist, prefix, kArr, lamArr, done);
    // pass-1 histogram + compaction + inline select1
    hist1_kernel<<<dim3(NH1B, 2), b256, 0, stream>>>(
        cd1, hist, prefix, cand, bcnt, kArr, lamArr, done);
    // pass-2 histogram over candidates + inline select2 (computes lambda)
    hist2_kernel<<<dim3(NH1B, 2), b256, 0, stream>>>(
        cand, hist, prefix, bcnt, kArr, lamArr, done);
    // fused 3-level reconstruction + output
    idwt_fused<<<dim3((L0 + NF0 - 1) / NF0, 2), b256, 0, stream>>>(
        ca3, cd3, cd2, cd1, trend, res, out, lamArr);
}

// Round 6
// 295.606 us; speedup vs baseline: 1.9952x; 1.0892x over previous
//
#include <hip/hip_runtime.h>
#include <math.h>

#define BB 32
#define TT 720
#define NNN 321
#define KK 25
#define PP 12
#define TCH 24   // T-chunk per thread in mavg; 720 = 30 * 24

constexpr int L0 = BB * TT * NNN;          // 7,395,840
constexpr int L1 = (L0 + 15) / 2;          // 3,697,927
constexpr int L2 = (L1 + 15) / 2;          // 1,848,971
constexpr int L3 = (L2 + 15) / 2;          // 924,493
// padded strides (even -> float2/float4 alignment for BOTH signals' slabs).
// pad element is never read: all consumers bound indices < L.
constexpr int L1P = L1 + 1;                // 3,697,928 (%4==0)
constexpr int L2P = L2 + 1;                // 1,848,972 (%4==0)
constexpr int L3P = L3 + 1;                // 924,494  (%2==0)
constexpr unsigned KMED = (unsigned)((L1 - 1) / 2 + 1);
constexpr float AA = 0.85f;

// median pass-1 compaction geometry: 512 blocks, contiguous chunks
constexpr int NH1B = 512;                       // hist1 blocks per signal
constexpr int CH   = (L1 + NH1B - 1) / NH1B;    // 7223 elements/block
constexpr int CANDSZ = NH1B * CH;               // per-signal cand region

// fused-kernel tile params
#define NC3 1024                            // ca3 outputs per block in dwt123
constexpr int LEN2T = 2 * NC3 + 32;         // 2080 ca2 tile slots (raw T0 = 2*C0-14)
constexpr int LEN1T = 4 * NC3 + 80;         // 4176 ca1 tile slots
#define NF0 4096                            // final outputs per block in idwt_fused
constexpr int N1T = NF0 / 2 + 8;            // 2056 rec1 tile
constexpr int N2T = N1T / 2 + 7;            // 1035 rec2 tile
constexpr int NQ3 = (N2T + 1) / 2;          // 518 rec2 pairs

// 16-tap analysis low-pass (from reference)
constexpr float DLO[16] = {
    -0.0033824159510061256f, -0.0005421323317911481f, 0.03169508781149298f,
    0.007607487324917605f,  -0.1432942383508097f,    -0.061273359067658524f,
    0.4813596512583722f,     0.7771857517005235f,     0.36444189483533895f,
    -0.05194583810770904f,  -0.027219029917056003f,   0.049137179673607506f,
    0.003808752013890615f,  -0.01495225833704823f,   -0.0003029205147213668f,
    0.0018899503327594609f };

// ---------------- inline radix-select (run by last block of producer) ----------
// 11/12/9-bit split (2048 / 4096 / 512 bins). Reads hist via atomicExch
// (device-scope, cross-XCD safe) which also re-zeroes bins for the next pass.
__device__ void select_body(unsigned* hist, unsigned* prefix, unsigned* kArr,
                            float* lamArr, int nbins, int shift) {
    int t = threadIdx.x;
    int chunk = nbins >> 8;                 // 8 / 16 / 2
    __shared__ unsigned wsum[4];
    for (int s = 0; s < 2; ++s) {
        unsigned loc[16];
        unsigned* hs = hist + s * 4096 + t * chunk;
        unsigned csum = 0;
        for (int j = 0; j < chunk; ++j) { loc[j] = atomicExch(&hs[j], 0u); csum += loc[j]; }
        unsigned v = csum;
        int lane = t & 63, wv = t >> 6;
#pragma unroll
        for (int off = 1; off < 64; off <<= 1) {
            unsigned u = (unsigned)__shfl_up((int)v, off, 64);
            if (lane >= off) v += u;
        }
        if (lane == 63) wsum[wv] = v;
        __syncthreads();
        unsigned base = 0;
        for (int w2 = 0; w2 < wv; ++w2) base += wsum[w2];
        unsigned incl = base + v, excl = incl - csum;
        unsigned k = kArr[s];
        if (excl < k && incl >= k) {
            unsigned run = excl;
            for (int j = 0; j < chunk; ++j) {
                if (run < k && run + loc[j] >= k) {
                    unsigned digit = (unsigned)(t * chunk + j);
                    unsigned npref = prefix[s] | (digit << shift);
                    prefix[s] = npref;
                    kArr[s] = k - run;
                    if (shift == 0) {
                        float med = __uint_as_float(npref);
                        lamArr[s] = (med / 0.6745f) * sqrtf(2.0f * logf((float)L0));
                    }
                    break;
                }
                run += loc[j];
            }
        }
        __syncthreads();                    // wsum reuse for next s
    }
}

// last-block detection. NO __threadfence(): on gfx950 a device-scope fence
// emits an L2 writeback+invalidate (per-XCD L2s non-coherent) — measured
// +180us across 1806 blocks in R3. Not needed: all cross-block data consumed
// by select_body travels via device-scope atomics, and __syncthreads() drains
// vmcnt before s_barrier, so this block's hist atomics have completed at the
// coherence point before the done-counter increment.
__device__ bool i_am_last(unsigned* done, unsigned nBlocks) {
    __shared__ int amLast;
    __syncthreads();
    if (threadIdx.x == 0) {
        unsigned prev = atomicAdd(done, 1u);
        amLast = (prev == nBlocks - 1) ? 1 : 0;
    }
    __syncthreads();
    return amLast != 0;
}

// ---------------- moving average + residual (+ median state init) ---------------
__global__ void mavg_kernel(const float* __restrict__ x,
                            float* __restrict__ trend,
                            float* __restrict__ res,
                            unsigned* __restrict__ hist,
                            unsigned* __restrict__ prefix,
                            unsigned* __restrict__ kArr,
                            unsigned* __restrict__ done) {
    constexpr int NCH = TT / TCH;                 // 30
    int gid = blockIdx.x * blockDim.x + threadIdx.x;
    if (gid < 8192) hist[gid] = 0;
    if (gid < 2) { prefix[gid] = 0; kArr[gid] = KMED; }
    if (gid < 3) done[gid] = 0;
    if (gid >= BB * NCH * NNN) return;
    int n    = gid % NNN;
    int rest = gid / NNN;
    int ch   = rest % NCH;
    int b    = rest / NCH;
    int t0   = ch * TCH;
    const float* xb = x + (size_t)b * TT * NNN + n;
    float sum = 0.f;
#pragma unroll
    for (int dt = -PP; dt <= PP; ++dt) {
        int tt = t0 + dt;
        tt = tt < 0 ? 0 : (tt >= TT ? TT - 1 : tt);
        sum += xb[(size_t)tt * NNN];
    }
    size_t base = (size_t)b * TT * NNN + (size_t)t0 * NNN + n;
    for (int i = 0; i < TCH; ++i) {
        int t = t0 + i;
        float tr = sum * (1.0f / (float)KK);
        size_t idx = base + (size_t)i * NNN;
        trend[idx] = tr;
        res[idx] = xb[(size_t)t * NNN] - tr;
        int tp = t + 1 + PP; if (tp > TT - 1) tp = TT - 1;
        int tm = t - PP;     if (tm < 0)      tm = 0;
        sum += xb[(size_t)tp * NNN] - xb[(size_t)tm * NNN];
    }
}

// ---------------- fused DWT levels 1+2+3 (+ hist pass 0 + inline select0) -------
// LDS = s1 (16.7KB) + s2 (8.3KB) = 25KB -> 6 blocks/CU. The 2048-bin pass-0
// histogram ALIASES s2 (dead until stage 2; flushed before stage 2 writes it).
// Stage 1 loads via float4 (was 18 scalar dword loads with 4x L1 read
// amplification from the 16B lane stride). Stages 2/3 pair-wise with float2
// LDS reads. cd1/cd2/ca3/cd3 stores via float2 (even padded strides).
__global__ void dwt123_kernel(const float* __restrict__ trend,
                              const float* __restrict__ res,
                              float* __restrict__ cd1,
                              float* __restrict__ cd2,
                              float* __restrict__ ca3,
                              float* __restrict__ cd3,
                              unsigned* __restrict__ hist,
                              unsigned* __restrict__ prefix,
                              unsigned* __restrict__ kArr,
                              float* __restrict__ lamArr,
                              unsigned* __restrict__ done) {
    int s = blockIdx.y;
    int C0 = blockIdx.x * NC3;
    const float* a0 = s ? res : trend;           // level-1 input, length L0
    __shared__ float s1[LEN1T];                  // ca1 tile
    __shared__ float s2[LEN2T];                  // ca2 tile (alias: pass-0 hist)
    unsigned* shst = (unsigned*)s2;              // 2048 bins <= LEN2T slots

    for (int b = threadIdx.x; b < 2048; b += 256) shst[b] = 0;
    __syncthreads();

    int T0 = 2 * C0 - 14;
    int S1 = 4 * C0 - 42; if (S1 < 0) S1 = 0;
    int E1 = 2 * (T0 + LEN2T) + 2; if (E1 > L1) E1 = L1;
    int len1 = E1 - S1;                          // <= LEN1T
    float* pcd1 = cd1 + (size_t)s * L1P;

    // ---- stage 1: level-1 DWT -> s1 (ca) + global cd1 core (+ LDS hist)
    int npair = (len1 + 1) / 2;
    for (int ip = threadIdx.x; ip < npair; ip += 256) {
        int i = 2 * ip;
        int o = S1 + i;                          // pair (o, o+1); o even
        float slo0, shi0, slo1, shi1;
        if (2 * o - 16 >= 0 && 2 * o + 3 < L0) {
            // window [2o-16, 2o+3]: 16B-aligned (o even, a0 16B-aligned)
            const float4* p4 = (const float4*)(a0 + 2 * o - 16);
            float4 qa = p4[0], qb = p4[1], qc = p4[2], qd = p4[3], qe = p4[4];
            float v[20] = { qa.x,qa.y,qa.z,qa.w, qb.x,qb.y,qb.z,qb.w,
                            qc.x,qc.y,qc.z,qc.w, qd.x,qd.y,qd.z,qd.w,
                            qe.x,qe.y,qe.z,qe.w };
            slo0 = shi0 = slo1 = shi1 = 0.f;
#pragma unroll
            for (int j = 0; j < 16; ++j) {
                float h = (j & 1) ? DLO[15 - j] : -DLO[15 - j];
                slo0 = fmaf(DLO[j], v[17 - j], slo0);   // old v[15-j] (+2 shift)
                shi0 = fmaf(h,      v[17 - j], shi0);
                slo1 = fmaf(DLO[j], v[19 - j], slo1);   // old v[17-j]
                shi1 = fmaf(h,      v[19 - j], shi1);
            }
        } else {
            float acc[2][2];
#pragma unroll
            for (int q = 0; q < 2; ++q) {
                int oo = o + q;
                float slo = 0.f, shi = 0.f;
                int bidx = 2 * oo + 1;
#pragma unroll
                for (int j = 0; j < 16; ++j) {
                    int idx = bidx - j;
                    if (idx < 0) idx = -1 - idx;
                    if (idx >= L0) idx = 2 * L0 - 1 - idx;
                    float v = a0[idx];
                    slo = fmaf(DLO[j], v, slo);
                    float h = (j & 1) ? DLO[15 - j] : -DLO[15 - j];
                    shi = fmaf(h, v, shi);
                }
                acc[q][0] = slo; acc[q][1] = shi;
            }
            slo0 = acc[0][0]; shi0 = acc[0][1];
            slo1 = acc[1][0]; shi1 = acc[1][1];
        }
        s1[i] = slo0;
        if (i + 1 < len1) s1[i + 1] = slo1;
        // core bounds are even; o even -> o and o+1 are in-core together
        if (o >= 4 * C0 && o < 4 * C0 + 4 * NC3) {
            unsigned u0 = __float_as_uint(fabsf(shi0));
            if (i + 1 < len1) {
                *(float2*)(pcd1 + o) = make_float2(shi0, shi1);
                unsigned u1 = __float_as_uint(fabsf(shi1));
                atomicAdd(&shst[u0 >> 21], 1u);
                atomicAdd(&shst[u1 >> 21], 1u);
            } else {
                pcd1[o] = shi0;
                atomicAdd(&shst[u0 >> 21], 1u);
            }
        }
    }
    __syncthreads();

    // flush pass-0 histogram, then free the alias for s2
    for (int b = threadIdx.x; b < 2048; b += 256) {
        unsigned c = shst[b];
        if (c) atomicAdd(&hist[s * 4096 + b], c);
    }
    __syncthreads();

    // ---- stage 2: level-2 DWT from s1 -> s2 (ca2) + global cd2 core
    float* pcd2 = cd2 + (size_t)s * L2P;
    for (int ip = threadIdx.x; ip < LEN2T / 2; ip += 256) {
        int i0 = 2 * ip;
        int e0 = T0 + i0;                        // even
        int e1 = e0 + 1;
        if (2 * e0 - 14 >= 0 && 2 * e1 + 1 < L1 && e1 < L2) {
            // window s1[2e0-14-S1 .. 2e0+3-S1], even offset -> float2
            const float2* wp2 = (const float2*)(s1 + (2 * e0 - 14 - S1));
            float w[18];
#pragma unroll
            for (int j = 0; j < 9; ++j) { float2 t2 = wp2[j]; w[2*j] = t2.x; w[2*j+1] = t2.y; }
            float slo0 = 0.f, shi0 = 0.f, slo1 = 0.f, shi1 = 0.f;
#pragma unroll
            for (int j = 0; j < 16; ++j) {
                float h = (j & 1) ? DLO[15 - j] : -DLO[15 - j];
                slo0 = fmaf(DLO[j], w[15 - j], slo0);
                shi0 = fmaf(h,      w[15 - j], shi0);
                slo1 = fmaf(DLO[j], w[17 - j], slo1);
                shi1 = fmaf(h,      w[17 - j], shi1);
            }
            s2[i0] = slo0; s2[i0 + 1] = slo1;
            if (e0 >= 2 * C0 && e0 < 2 * C0 + 2 * NC3)
                *(float2*)(pcd2 + e0) = make_float2(shi0, shi1);
        } else {
#pragma unroll
            for (int q = 0; q < 2; ++q) {
                int i = i0 + q;
                int e = T0 + i;
                if (e < 0 || e >= L2) continue;
                int base = 2 * e + 1;
                float slo = 0.f, shi = 0.f;
#pragma unroll
                for (int j = 0; j < 16; ++j) {
                    int idx = base - j;
                    if (idx < 0) idx = -1 - idx;
                    if (idx >= L1) idx = 2 * L1 - 1 - idx;
                    float v = s1[idx - S1];
                    slo = fmaf(DLO[j], v, slo);
                    float h = (j & 1) ? DLO[15 - j] : -DLO[15 - j];
                    shi = fmaf(h, v, shi);
                }
                s2[i] = slo;
                if (e >= 2 * C0 && e < 2 * C0 + 2 * NC3) pcd2[e] = shi;
            }
        }
    }
    __syncthreads();
    // reflection fill for out-of-range ca2 tile slots (edges only)
    for (int i = threadIdx.x; i < LEN2T; i += 256) {
        int e = T0 + i;
        if (e < 0)        s2[i] = s2[(-1 - e) - T0];
        else if (e >= L2) s2[i] = s2[(2 * L2 - 1 - e) - T0];
    }
    __syncthreads();
    // ---- stage 3: level-3 DWT from s2 (always in-tile; pair-wise float2)
    float* pca3 = ca3 + (size_t)s * L3P;
    float* pcd3 = cd3 + (size_t)s * L3P;
    for (int ip = threadIdx.x; ip < NC3 / 2; ip += 256) {
        int i0 = 2 * ip;
        int o0 = C0 + i0;                        // even
        if (o0 >= L3) break;
        const float2* wp2 = (const float2*)(s2 + i0 * 2);   // even offset
        float w[18];
#pragma unroll
        for (int j = 0; j < 9; ++j) { float2 t2 = wp2[j]; w[2*j] = t2.x; w[2*j+1] = t2.y; }
        float slo0 = 0.f, shi0 = 0.f, slo1 = 0.f, shi1 = 0.f;
#pragma unroll
        for (int j = 0; j < 16; ++j) {
            float h = (j & 1) ? DLO[15 - j] : -DLO[15 - j];
            slo0 = fmaf(DLO[j], w[15 - j], slo0);
            shi0 = fmaf(h,      w[15 - j], shi0);
            slo1 = fmaf(DLO[j], w[17 - j], slo1);
            shi1 = fmaf(h,      w[17 - j], shi1);
        }
        if (o0 + 1 < L3) {
            *(float2*)(pca3 + o0) = make_float2(slo0, slo1);
            *(float2*)(pcd3 + o0) = make_float2(shi0, shi1);
        } else {
            pca3[o0] = slo0; pcd3[o0] = shi0;
        }
    }

    // ---- last block runs select pass 0 (top 11 bits)
    if (i_am_last(done + 0, gridDim.x * gridDim.y))
        select_body(hist, prefix, kArr, lamArr, 2048, 21);
}

// ---------------- soft threshold ----------------
__device__ __forceinline__ float sthr(float d, float lam, float alam) {
    float ad = fabsf(d);
    return (ad >= lam) ? copysignf(ad - alam, d) : 0.f;
}

// ---------------- fused 3-level IDWT + final outputs ----------------
__global__ void idwt_fused(const float* __restrict__ ca3,
                           const float* __restrict__ cd3,
                           const float* __restrict__ cd2,
                           const float* __restrict__ cd1,
                           const float* __restrict__ trend,
                           const float* __restrict__ res,
                           float* __restrict__ out,
                           const float* __restrict__ lamArr) {
    int s = blockIdx.y;
    int F0 = blockIdx.x * NF0;
    float lam = lamArr[s], alam = AA * lam;
    const float* pa3 = ca3 + (size_t)s * L3P;
    const float* pd3 = cd3 + (size_t)s * L3P;
    const float* pd2 = cd2 + (size_t)s * L2P;
    const float* pd1 = cd1 + (size_t)s * L1P;
    __shared__ float r2[N2T + 1];
    __shared__ float r1[N1T];
    int A1 = F0 >> 1, A2 = F0 >> 2, Q3 = F0 >> 3;
    // stage rec2 tile from ca3/cd3 (level 3 -> 2)
    for (int i = threadIdx.x; i < NQ3; i += 256) {
        int q3 = Q3 + i;
        float a0 = 0.f, a1 = 0.f;
#pragma unroll
        for (int p = 0; p < 8; ++p) {
            int idx = q3 + p; if (idx > L3 - 1) idx = L3 - 1;
            float a = pa3[idx];
            float d = sthr(pd3[idx], lam, alam);
            a0 = fmaf(a, DLO[2 * p + 1], a0);
            a0 = fmaf(d, DLO[14 - 2 * p], a0);
            a1 = fmaf(a, DLO[2 * p], a1);
            a1 = fmaf(d, -DLO[15 - 2 * p], a1);
        }
        r2[2 * i] = a0; r2[2 * i + 1] = a1;
    }
    __syncthreads();
    // stage rec1 tile from rec2(LDS) + cd2(global) (level 2 -> 1)
    for (int i = threadIdx.x; i < N1T / 2; i += 256) {
        int q2 = A2 + i;
        float a0 = 0.f, a1 = 0.f;
#pragma unroll
        for (int p = 0; p < 8; ++p) {
            float a = r2[i + p];
            int idx = q2 + p; if (idx > L2 - 1) idx = L2 - 1;
            float d = sthr(pd2[idx], lam, alam);
            a0 = fmaf(a, DLO[2 * p + 1], a0);
            a0 = fmaf(d, DLO[14 - 2 * p], a0);
            a1 = fmaf(a, DLO[2 * p], a1);
            a1 = fmaf(d, -DLO[15 - 2 * p], a1);
        }
        r1[2 * i] = a0; r1[2 * i + 1] = a1;
    }
    __syncthreads();
    // final level from rec1(LDS) + cd1(global): 4 outputs/thread, float4 I/O
    const float* orig = s ? res : trend;
    float* o_diff = out + (size_t)(2 * s) * L0;
    float* o_nn   = out + (size_t)(2 * s + 1) * L0;
    for (int i = threadIdx.x; i < NF0 / 4; i += 256) {
        int ii = 2 * i;                      // r1-local index of first q1
        int q1 = A1 + ii;                    // even
        int r0 = 2 * q1;                     // multiple of 4; L0 % 4 == 0
        if (r0 >= L0) break;
        float d[9];
        if (q1 + 9 <= L1) {
            const float2* pp = (const float2*)(pd1 + q1);  // even -> 8B aligned
            float2 e0 = pp[0], e1 = pp[1], e2 = pp[2], e3 = pp[3];
            d[0] = sthr(e0.x, lam, alam); d[1] = sthr(e0.y, lam, alam);
            d[2] = sthr(e1.x, lam, alam); d[3] = sthr(e1.y, lam, alam);
            d[4] = sthr(e2.x, lam, alam); d[5] = sthr(e2.y, lam, alam);
            d[6] = sthr(e3.x, lam, alam); d[7] = sthr(e3.y, lam, alam);
            d[8] = sthr(pd1[q1 + 8], lam, alam);
        } else {
#pragma unroll
            for (int p = 0; p < 9; ++p) {
                int idx = q1 + p; if (idx > L1 - 1) idx = L1 - 1;
                d[p] = sthr(pd1[idx], lam, alam);
            }
        }
        float a0 = 0.f, a1 = 0.f, b0 = 0.f, b1 = 0.f;
#pragma unroll
        for (int p = 0; p < 8; ++p) {
            float a  = r1[ii + p];
            float ab = r1[ii + 1 + p];
            a0 = fmaf(a,      DLO[2 * p + 1], a0);
            a0 = fmaf(d[p],   DLO[14 - 2 * p], a0);
            a1 = fmaf(a,      DLO[2 * p], a1);
            a1 = fmaf(d[p],  -DLO[15 - 2 * p], a1);
            b0 = fmaf(ab,     DLO[2 * p + 1], b0);
            b0 = fmaf(d[p+1], DLO[14 - 2 * p], b0);
            b1 = fmaf(ab,     DLO[2 * p], b1);
            b1 = fmaf(d[p+1],-DLO[15 - 2 * p], b1);
        }
        float4 o4 = *(const float4*)(orig + r0);
        float4 nn; nn.x = a0; nn.y = a1; nn.z = b0; nn.w = b1;
        float4 df; df.x = o4.x - a0; df.y = o4.y - a1; df.z = o4.z - b0; df.w = o4.w - b1;
        *(float4*)(o_nn + r0)   = nn;
        *(float4*)(o_diff + r0) = df;
    }
}

// pass 1: contiguous per-block chunks; filter on 11-bit prefix, histogram
// next 12 bits (bits 20..9), compact survivors into PRIVATE cand region.
__global__ void hist1_kernel(const float* __restrict__ d,
                             unsigned* __restrict__ hist,
                             unsigned* __restrict__ prefix,
                             unsigned* __restrict__ cand,
                             unsigned* __restrict__ bcnt,
                             unsigned* __restrict__ kArr,
                             float* __restrict__ lamArr,
                             unsigned* __restrict__ done) {
    int s = blockIdx.y;
    int blk = blockIdx.x;
    const float* ds = d + (size_t)s * L1P;
    unsigned* cs = cand + (size_t)s * CANDSZ + (size_t)blk * CH;
    __shared__ unsigned sh[4096];
    __shared__ unsigned slocal;
    for (int b = threadIdx.x; b < 4096; b += 256) sh[b] = 0;
    if (threadIdx.x == 0) slocal = 0;
    __syncthreads();
    unsigned pref = prefix[s] >> 21;
    int i0 = blk * CH;
    int i1 = i0 + CH; if (i1 > L1) i1 = L1;
    for (int i = i0 + threadIdx.x; i < i1; i += 256) {
        unsigned u = __float_as_uint(fabsf(ds[i]));
        if ((u >> 21) == pref) {
            atomicAdd(&sh[(u >> 9) & 0xFFFu], 1u);
            unsigned pos = atomicAdd(&slocal, 1u);
            cs[pos] = u;
        }
    }
    __syncthreads();
    if (threadIdx.x == 0) bcnt[s * NH1B + blk] = slocal;
    for (int b = threadIdx.x; b < 4096; b += 256) {
        unsigned c = sh[b];
        if (c) atomicAdd(&hist[s * 4096 + b], c);
    }
    if (i_am_last(done + 1, gridDim.x * gridDim.y))
        select_body(hist, prefix, kArr, lamArr, 4096, 9);
}

// pass 2: last 9 bits (512 bins) over the compacted candidate lists (tiny).
__global__ void hist2_kernel(const unsigned* __restrict__ cand,
                             unsigned* __restrict__ hist,
                             unsigned* __restrict__ prefix,
                             const unsigned* __restrict__ bcnt,
                             unsigned* __restrict__ kArr,
                             float* __restrict__ lamArr,
                             unsigned* __restrict__ done) {
    int s = blockIdx.y;
    int blk = blockIdx.x;
    const unsigned* cs = cand + (size_t)s * CANDSZ + (size_t)blk * CH;
    __shared__ unsigned sh[512];
    sh[threadIdx.x] = 0; sh[threadIdx.x + 256] = 0;
    __syncthreads();
    unsigned pref = prefix[s] >> 9;
    unsigned n = bcnt[s * NH1B + blk];
    for (unsigned i = threadIdx.x; i < n; i += 256) {
        unsigned u = cs[i];
        if ((u >> 9) == pref) atomicAdd(&sh[u & 0x1FFu], 1u);
    }
    __syncthreads();
    for (int b = threadIdx.x; b < 512; b += 256) {
        unsigned c = sh[b];
        if (c) atomicAdd(&hist[s * 4096 + b], c);
    }
    if (i_am_last(done + 2, gridDim.x * gridDim.y))
        select_body(hist, prefix, kArr, lamArr, 512, 0);
}

extern "C" void kernel_launch(void* const* d_in, const int* in_sizes, int n_in,
                              void* d_out, int out_size, void* d_ws, size_t ws_size,
                              hipStream_t stream) {
    const float* x = (const float*)d_in[0];
    float* out = (float*)d_out;
    float* w = (float*)d_ws;

    float* trend = w;
    float* res   = w + (size_t)L0;
    float* cd1   = w + 2 * (size_t)L0;
    float* cd2   = cd1 + 2 * (size_t)L1P;
    float* ca3   = cd2 + 2 * (size_t)L2P;
    float* cd3   = ca3 + 2 * (size_t)L3P;
    unsigned* cand   = (unsigned*)(cd3 + 2 * (size_t)L3P);
    unsigned* hist   = cand + 2 * (size_t)CANDSZ;
    unsigned* prefix = hist + 8192;
    unsigned* kArr   = prefix + 2;
    float*    lamArr = (float*)(kArr + 2);
    unsigned* bcnt   = (unsigned*)(lamArr + 2);   // 2 * NH1B entries
    unsigned* done   = bcnt + 2 * NH1B;           // 3 done-counters

    dim3 b256(256);

    {
        int nthreads = BB * (TT / TCH) * NNN;
        mavg_kernel<<<(nthreads + 255) / 256, b256, 0, stream>>>(
            x, trend, res, hist, prefix, kArr, done);
    }
    // fused 3-level decomposition + pass-0 histogram + inline select0
    dwt123_kernel<<<dim3((L3 + NC3 - 1) / NC3, 2), b256, 0, stream>>>(
        trend, res, cd1, cd2, ca3, cd3, hist, prefix, kArr, lamArr, done);
    // pass-1 histogram + compaction + inline select1
    hist1_kernel<<<dim3(NH1B, 2), b256, 0, stream>>>(
        cd1, hist, prefix, cand, bcnt, kArr, lamArr, done);
    // pass-2 histogram over candidates + inline select2 (computes lambda)
    hist2_kernel<<<dim3(NH1B, 2), b256, 0, stream>>>(
        cand, hist, prefix, bcnt, kArr, lamArr, done);
    // fused 3-level reconstruction + output
    idwt_fused<<<dim3((L0 + NF0 - 1) / NF0, 2), b256, 0, stream>>>(
        ca3, cd3, cd2, cd1, trend, res, out, lamArr);
}